// Round 1
// baseline (2878.935 us; speedup 1.0000x reference)
//
#include <hip/hip_runtime.h>
#include <hip/hip_bf16.h>
#include <math.h>

// ChebyNet: 2-layer ChebConv (K=4), N=100000, E=1600000, F 32->16->10, log_softmax.
//
// R22: full chain fusion. zgen + 4x prop_cl + final1 + final2 were 7 kernels,
// each re-loading rowbeg/rowend/dis/d2/inv and psrc before its gathers (2-deep
// dependent-load prologue per phase). Fused into one persistent kernel
// (1024 blocks x 256 thr = exactly 4 blocks/CU via __launch_bounds__(256,4);
// 16 waves/CU, VGPR<=128, LDS 12.4KB -> co-residency guaranteed) with
// software grid barriers (device-scope atomic + __threadfence for cross-XCD
// visibility). Per-thread persistent state across all phases: node metadata
// + first 8 psrc entries (covers ~90% of edges at mean degree 16) in
// registers. Balanced node partition (slot*N>>16) so all blocks reach each
// barrier with equal work. CSR build (binned_scatter/bucket_place) unchanged.
// R18-R21 recap: Clenshaw in 16-feature bf16 U-space, bucket CSR, src-quartile
// edge ordering, deg-0 exact fallback.

#define BLK 256
#define BLKP 512
#define NBUCK_MAX 256   // buckets = ceil(N/512); requires N <= 131072
#define CHUNK 4096      // edges per binned_scatter block
#define CAPB 16384      // fixed capacity per bucket region in tmp/psrc
#define PLACE_CAP 10240 // LDS staging capacity in bucket_place (avg bucket 8192)

#define CHAIN_BLOCKS 1024
#define CHAIN_THREADS 256
// slots = 1024*256/4 = 65536; node range per slot = [slot*N>>16, (slot+1)*N>>16)

// ---------- bf16 helpers (storage-only quantization) ----------
__device__ inline unsigned short f32_to_bf16_rne(float f) {
    unsigned int u = __float_as_uint(f);
    unsigned int rounding = 0x7FFFu + ((u >> 16) & 1u);
    return (unsigned short)((u + rounding) >> 16);
}
__device__ inline unsigned int pack_bf16x2(float a, float b) {
    return (unsigned int)f32_to_bf16_rne(a) | ((unsigned int)f32_to_bf16_rne(b) << 16);
}
__device__ inline void unpack8(const uint4 u, float* f) {
    const unsigned int* p = &u.x;
#pragma unroll
    for (int j = 0; j < 4; j++) {
        unsigned int w = p[j];
        f[2 * j]     = __uint_as_float(w << 16);
        f[2 * j + 1] = __uint_as_float(w & 0xFFFF0000u);
    }
}
__device__ inline void add8(const uint4 u, float* acc) {
    const unsigned int* p = &u.x;
#pragma unroll
    for (int j = 0; j < 4; j++) {
        unsigned int w = p[j];
        acc[2 * j]     += __uint_as_float(w << 16);
        acc[2 * j + 1] += __uint_as_float(w & 0xFFFF0000u);
    }
}
__device__ inline uint4 pack8(const float* r) {
    uint4 o;
    o.x = pack_bf16x2(r[0], r[1]);
    o.y = pack_bf16x2(r[2], r[3]);
    o.z = pack_bf16x2(r[4], r[5]);
    o.w = pack_bf16x2(r[6], r[7]);
    return o;
}

// gather-sum over psrc[b,e) of vb chunk c
__device__ inline void gather_sum(const int* __restrict__ psrc, int b, int e,
                                  const uint4* __restrict__ vb, int c, float* acc) {
    int i = b;
    for (; i + 7 < e; i += 8) {
        int s0 = psrc[i],     s1 = psrc[i + 1], s2 = psrc[i + 2], s3 = psrc[i + 3];
        int s4 = psrc[i + 4], s5 = psrc[i + 5], s6 = psrc[i + 6], s7 = psrc[i + 7];
        uint4 a0 = vb[(size_t)s0 * 2 + c];
        uint4 a1 = vb[(size_t)s1 * 2 + c];
        uint4 a2 = vb[(size_t)s2 * 2 + c];
        uint4 a3 = vb[(size_t)s3 * 2 + c];
        uint4 a4 = vb[(size_t)s4 * 2 + c];
        uint4 a5 = vb[(size_t)s5 * 2 + c];
        uint4 a6 = vb[(size_t)s6 * 2 + c];
        uint4 a7 = vb[(size_t)s7 * 2 + c];
        add8(a0, acc); add8(a1, acc); add8(a2, acc); add8(a3, acc);
        add8(a4, acc); add8(a5, acc); add8(a6, acc); add8(a7, acc);
    }
    for (; i + 3 < e; i += 4) {
        int s0 = psrc[i], s1 = psrc[i + 1], s2 = psrc[i + 2], s3 = psrc[i + 3];
        uint4 a0 = vb[(size_t)s0 * 2 + c];
        uint4 a1 = vb[(size_t)s1 * 2 + c];
        uint4 a2 = vb[(size_t)s2 * 2 + c];
        uint4 a3 = vb[(size_t)s3 * 2 + c];
        add8(a0, acc); add8(a1, acc); add8(a2, acc); add8(a3, acc);
    }
    for (; i < e; i++) add8(vb[(size_t)psrc[i] * 2 + c], acc);
}

// ---------- CSR build (fixed-capacity buckets) ----------
__global__ __launch_bounds__(BLK)
void binned_scatter_kernel(const int* __restrict__ src, const int* __restrict__ dst,
                           int* __restrict__ bfill, int* __restrict__ tmp,
                           int E, int nbuck) {
    __shared__ int cnt[NBUCK_MAX];
    __shared__ int lofs[NBUCK_MAX + 1];
    __shared__ int pos[NBUCK_MAX];
    __shared__ int gbase[NBUCK_MAX];
    __shared__ int stage[CHUNK];
    __shared__ unsigned char bkt[CHUNK];

    int tid = threadIdx.x;
    int e0 = blockIdx.x * CHUNK;
    int nE = min(CHUNK, E - e0);

    for (int b = tid; b < nbuck; b += BLK) { cnt[b] = 0; pos[b] = 0; }
    __syncthreads();

    for (int i = tid; i < nE; i += BLK) {
        int d = dst[e0 + i];
        atomicAdd(&cnt[d >> 9], 1);
    }
    __syncthreads();

    {
        int v = (tid < nbuck) ? cnt[tid] : 0;
        lofs[tid] = v;
        __syncthreads();
        for (int off = 1; off < BLK; off <<= 1) {
            int t = (tid >= off) ? lofs[tid - off] : 0;
            __syncthreads();
            lofs[tid] += t;
            __syncthreads();
        }
        int incl = lofs[tid];
        __syncthreads();
        lofs[tid] = incl - v;
        if (tid == 0) lofs[nbuck] = nE;
        if (tid < nbuck && v > 0)
            gbase[tid] = tid * CAPB + atomicAdd(&bfill[tid], v);
    }
    __syncthreads();

    for (int i = tid; i < nE; i += BLK) {
        int s = src[e0 + i];
        int d = dst[e0 + i];
        int b = d >> 9;
        int slot = lofs[b] + atomicAdd(&pos[b], 1);
        stage[slot] = (s << 9) | (d & 511);
        bkt[slot] = (unsigned char)b;
    }
    __syncthreads();

    for (int i = tid; i < nE; i += BLK) {
        int b = bkt[i];
        tmp[gbase[b] + (i - lofs[b])] = stage[i];
    }
}

// Phase 2: per-bucket degree count/scan -> rowbeg/rowend/dis/d2/inv;
// rank+stage+flush psrc with each node's edges ordered by src quartile.
__global__ __launch_bounds__(BLKP)
void bucket_place_kernel(const int* __restrict__ bfill, const int* __restrict__ tmp,
                         int* __restrict__ psrc, int* __restrict__ rowbeg,
                         int* __restrict__ rowend, float* __restrict__ dis,
                         float* __restrict__ d2, float* __restrict__ inv, int N) {
    __shared__ int cnt4[512 * 4];
    __shared__ int ofs[512];
    __shared__ int fill4[512 * 4];
    __shared__ int stage[PLACE_CAP];

    int b = blockIdx.x;
    int tid = threadIdx.x;
    int n0 = b << 9;
    int nn = min(512, N - n0);
    int S = b * CAPB;
    int tot = bfill[b];

    int t1 = N >> 2, t2 = N >> 1, t3 = t2 + t1;

    for (int i = tid; i < 512 * 4; i += BLKP) { cnt4[i] = 0; fill4[i] = 0; }
    __syncthreads();

    for (int i = tid; i < tot; i += BLKP) {
        int rec = tmp[S + i];
        int nl = rec & 511;
        int s = rec >> 9;
        int q = (s >= t2) ? ((s >= t3) ? 3 : 2) : ((s >= t1) ? 1 : 0);
        atomicAdd(&cnt4[nl * 4 + q], 1);
    }
    __syncthreads();

    int c0 = cnt4[tid * 4 + 0], c1 = cnt4[tid * 4 + 1];
    int c2 = cnt4[tid * 4 + 2], c3 = cnt4[tid * 4 + 3];
    int v = c0 + c1 + c2 + c3;
    cnt4[tid * 4 + 0] = 0;
    cnt4[tid * 4 + 1] = c0;
    cnt4[tid * 4 + 2] = c0 + c1;
    cnt4[tid * 4 + 3] = c0 + c1 + c2;
    ofs[tid] = v;
    __syncthreads();
    for (int off = 1; off < 512; off <<= 1) {
        int t = (tid >= off) ? ofs[tid - off] : 0;
        __syncthreads();
        ofs[tid] += t;
        __syncthreads();
    }
    int excl = ofs[tid] - v;
    __syncthreads();
    ofs[tid] = excl;
    if (tid < nn) {
        int n = n0 + tid;
        rowbeg[n] = S + excl;
        rowend[n] = S + excl + v;
        float fv = (float)v;
        dis[n] = (v > 0) ? rsqrtf(fv) : 0.0f;
        d2[n]  = (v > 0) ? 1.0f / fv : 0.0f;
        inv[n] = (v > 0) ? sqrtf(fv) : 0.0f;
    }
    __syncthreads();

    if (tot <= PLACE_CAP) {
        for (int i = tid; i < tot; i += BLKP) {
            int rec = tmp[S + i];
            int nl = rec & 511;
            int s = rec >> 9;
            int q = (s >= t2) ? ((s >= t3) ? 3 : 2) : ((s >= t1) ? 1 : 0);
            int slot = ofs[nl] + cnt4[nl * 4 + q] + atomicAdd(&fill4[nl * 4 + q], 1);
            stage[slot] = s;
        }
        __syncthreads();
        for (int i = tid; i < tot; i += BLKP) psrc[S + i] = stage[i];
    } else {
        for (int i = tid; i < tot; i += BLKP) {
            int rec = tmp[S + i];
            int nl = rec & 511;
            int s = rec >> 9;
            int q = (s >= t2) ? ((s >= t3) ? 3 : 2) : ((s >= t1) ? 1 : 0);
            int slot = S + ofs[nl] + cnt4[nl * 4 + q] + atomicAdd(&fill4[nl * 4 + q], 1);
            psrc[slot] = s;
        }
    }
}

// ---------- fused chain ----------

// Software grid barrier: all CHAIN_BLOCKS blocks are co-resident (4/CU).
// __threadfence() is the device-scope fence needed for cross-XCD visibility
// of the bf16 U-tables written in the previous phase.
__device__ inline void grid_barrier(int* __restrict__ gbar, int target) {
    __threadfence();
    __syncthreads();
    if (threadIdx.x == 0) {
        __hip_atomic_fetch_add(gbar, 1, __ATOMIC_ACQ_REL, __HIP_MEMORY_SCOPE_AGENT);
        while (__hip_atomic_load(gbar, __ATOMIC_ACQUIRE, __HIP_MEMORY_SCOPE_AGENT) < target) {
            __builtin_amdgcn_s_sleep(2);
        }
    }
    __syncthreads();
    __threadfence();
}

// Persistent per-node state, held in registers across all 7 phases.
struct NodeSt {
    int n, gb, ge, dz;
    float f, dn, iv;
    int pc[8];   // first 8 psrc entries of this lane's half-range (~90% of edges)
};

__device__ inline void node_init(NodeSt& s, int n, int hf,
                                 const int* __restrict__ rowbeg,
                                 const int* __restrict__ rowend,
                                 const float* __restrict__ dis,
                                 const float* __restrict__ d2,
                                 const float* __restrict__ inv,
                                 const int* __restrict__ psrc) {
    s.n = n;
    int beg = rowbeg[n], end = rowend[n];
    int mid = beg + ((end - beg) >> 1);
    s.gb = hf ? mid : beg;
    s.ge = hf ? end : mid;
    float dv = d2[n];
    s.dz = (dv == 0.0f) ? 1 : 0;
    s.f = -2.0f * dv;
    s.dn = dis[n];
    s.iv = inv[n];
    int m = s.ge - s.gb;
    if (m > 8) m = 8;
#pragma unroll
    for (int j = 0; j < 8; j++) s.pc[j] = (j < m) ? psrc[s.gb + j] : 0;
}

// gather using the register-cached first 8 indices, tail from global psrc
__device__ inline void gather_cached(const NodeSt& s, const int* __restrict__ psrc,
                                     const uint4* __restrict__ vb, int c, float* acc) {
    int cnt = s.ge - s.gb;
    int m = cnt < 8 ? cnt : 8;
    uint4 a[8];
#pragma unroll
    for (int j = 0; j < 8; j++) if (j < m) a[j] = vb[(size_t)s.pc[j] * 2 + c];
#pragma unroll
    for (int j = 0; j < 8; j++) if (j < m) add8(a[j], acc);
    if (cnt > 8) gather_sum(psrc, s.gb + 8, s.ge, vb, c, acc);
}

// phase Z: z_k = x @ W1[k]; lane (c,hf) computes k in {2hf, 2hf+1}, feats c*8..+7
__device__ inline void phaseZ(const NodeSt& s, const float* __restrict__ x,
                              const float* __restrict__ sW1, int c, int hf,
                              uint4* __restrict__ z0t, uint4* __restrict__ uz1t,
                              uint4* __restrict__ uz2t, uint4* __restrict__ uz3t,
                              uint4* __restrict__ z2rt) {
    const float4* x4 = reinterpret_cast<const float4*>(x + (size_t)s.n * 32);
    float a0[8], a1[8];
#pragma unroll
    for (int j = 0; j < 8; j++) { a0[j] = 0.f; a1[j] = 0.f; }
    const float* W = sW1 + hf * 1024 + c * 8;   // k = 2hf, stride 512 per k
#pragma unroll
    for (int q = 0; q < 8; q++) {
        float4 xa = x4[q];
        float xi[4] = {xa.x, xa.y, xa.z, xa.w};
#pragma unroll
        for (int u = 0; u < 4; u++) {
            const float* Wb = W + (q * 4 + u) * 16;
            float xv = xi[u];
#pragma unroll
            for (int j = 0; j < 8; j++) { a0[j] += xv * Wb[j]; a1[j] += xv * Wb[512 + j]; }
        }
    }
    size_t o = (size_t)s.n * 2 + c;
    float t[8];
    if (hf == 0) {
        z0t[o] = pack8(a0);
#pragma unroll
        for (int j = 0; j < 8; j++) t[j] = s.dn * a1[j];
        uz1t[o] = pack8(t);
    } else {
#pragma unroll
        for (int j = 0; j < 8; j++) t[j] = s.dn * a0[j];
        uz2t[o] = pack8(t);
        z2rt[o] = pack8(a0);
#pragma unroll
        for (int j = 0; j < 8; j++) t[j] = s.dn * a1[j];
        uz3t[o] = pack8(t);
    }
}

// Clenshaw prop: out = -2*d2*Sum vb[src] + addt (- subt)
template <bool SUB>
__device__ inline void phaseP(const NodeSt& s, const int* __restrict__ psrc,
                              const uint4* __restrict__ vb,
                              const uint4* __restrict__ addt,
                              const uint4* __restrict__ subt,
                              uint4* __restrict__ outb, int c, int hf) {
    float acc[8];
#pragma unroll
    for (int j = 0; j < 8; j++) acc[j] = 0.f;
    gather_cached(s, psrc, vb, c, acc);
#pragma unroll
    for (int j = 0; j < 8; j++) acc[j] += __shfl_xor(acc[j], 2);
    if (hf == 0) {
        size_t o = (size_t)s.n * 2 + c;
        float ad[8], r[8];
        unpack8(addt[o], ad);
        if (SUB) {
            float sb[8];
            unpack8(subt[o], sb);
#pragma unroll
            for (int j = 0; j < 8; j++) r[j] = s.f * acc[j] + ad[j] - sb[j];
        } else {
#pragma unroll
            for (int j = 0; j < 8; j++) r[j] = s.f * acc[j] + ad[j];
        }
        outb[o] = pack8(r);
    }
}

// final1: S = z0 - dis*Sum ub1[src] - inv*ub2 (deg-0: z0 - z2r); h = relu(b1+S);
// dense epilogue w_k = h @ W2[k]: lane (c,hf) computes k in {2hf,2hf+1}, cols c*8..+7
__device__ inline void phaseF1(const NodeSt& s, const int* __restrict__ psrc,
                               const uint4* __restrict__ ub1t,
                               const uint4* __restrict__ ub2t,
                               const uint4* __restrict__ z0t,
                               const uint4* __restrict__ z2rt,
                               const float* __restrict__ sW2,
                               const float* __restrict__ sb1,
                               uint4* __restrict__ w0t, uint4* __restrict__ uw1t,
                               uint4* __restrict__ uw2t, uint4* __restrict__ uw3t,
                               uint4* __restrict__ w2rt, int c, int hf) {
    float acc[8];
#pragma unroll
    for (int j = 0; j < 8; j++) acc[j] = 0.f;
    gather_cached(s, psrc, ub1t, c, acc);
#pragma unroll
    for (int j = 0; j < 8; j++) acc[j] += __shfl_xor(acc[j], 2);   // full sum, all 4 lanes
    size_t o = (size_t)s.n * 2 + c;
    float z0[8], hrow[8];
    unpack8(z0t[o], z0);
    if (s.dz) {
        float z2[8];
        unpack8(z2rt[o], z2);
#pragma unroll
        for (int j = 0; j < 8; j++) hrow[j] = fmaxf(sb1[c * 8 + j] + z0[j] - z2[j], 0.0f);
    } else {
        float bv[8];
        unpack8(ub2t[o], bv);
#pragma unroll
        for (int j = 0; j < 8; j++)
            hrow[j] = fmaxf(sb1[c * 8 + j] + z0[j] - s.dn * acc[j] - s.iv * bv[j], 0.0f);
    }
    // build full h16 on every lane via intra-pair exchange (static indexing)
    float h16[16];
#pragma unroll
    for (int j = 0; j < 8; j++) {
        float other = __shfl_xor(hrow[j], 1);
        h16[j]     = c ? other : hrow[j];
        h16[8 + j] = c ? hrow[j] : other;
    }
    float wa[8], wb[8];
#pragma unroll
    for (int o2 = 0; o2 < 8; o2++) { wa[o2] = 0.f; wb[o2] = 0.f; }
    const float* W = sW2 + hf * 512 + c * 8;   // k = 2hf, stride 256 per k
#pragma unroll
    for (int j = 0; j < 16; j++) {
        float hv = h16[j];
        const float* Wb = W + j * 16;
#pragma unroll
        for (int o2 = 0; o2 < 8; o2++) { wa[o2] += hv * Wb[o2]; wb[o2] += hv * Wb[256 + o2]; }
    }
    float t[8];
    if (hf == 0) {
        w0t[o] = pack8(wa);
#pragma unroll
        for (int o2 = 0; o2 < 8; o2++) t[o2] = s.dn * wb[o2];
        uw1t[o] = pack8(t);
    } else {
#pragma unroll
        for (int o2 = 0; o2 < 8; o2++) t[o2] = s.dn * wa[o2];
        uw2t[o] = pack8(t);
        w2rt[o] = pack8(wa);
#pragma unroll
        for (int o2 = 0; o2 < 8; o2++) t[o2] = s.dn * wb[o2];
        uw3t[o] = pack8(t);
    }
}

// final2: L = b2 + w0 - dis*Sum uv1[src] - inv*uv2 (deg-0: b2 + w0 - w2r);
// log_softmax across the (c=0,c=1) lane pair; static-indexed predicated loops.
__device__ inline void phaseF2(const NodeSt& s, const int* __restrict__ psrc,
                               const uint4* __restrict__ uv1t,
                               const uint4* __restrict__ uv2t,
                               const uint4* __restrict__ w0t,
                               const uint4* __restrict__ w2rt,
                               const float* __restrict__ sb2,
                               float* __restrict__ out, int c, int hf) {
    float acc[8];
#pragma unroll
    for (int j = 0; j < 8; j++) acc[j] = 0.f;
    gather_cached(s, psrc, uv1t, c, acc);
#pragma unroll
    for (int j = 0; j < 8; j++) acc[j] += __shfl_xor(acc[j], 2);
    if (hf == 0) {
        size_t o = (size_t)s.n * 2 + c;
        float w0[8], L[8];
        unpack8(w0t[o], w0);
        if (s.dz) {
            float w2[8];
            unpack8(w2rt[o], w2);
#pragma unroll
            for (int j = 0; j < 8; j++) L[j] = sb2[c * 8 + j] + w0[j] - w2[j];
        } else {
            float v2[8];
            unpack8(uv2t[o], v2);
#pragma unroll
            for (int j = 0; j < 8; j++)
                L[j] = sb2[c * 8 + j] + w0[j] - s.dn * acc[j] - s.iv * v2[j];
        }
        int nreal = (c == 0) ? 8 : 2;   // lane1 holds cols 8,9 (+6 pads)
        float m = -3.0e38f;
#pragma unroll
        for (int j = 0; j < 8; j++) if (j < nreal) m = fmaxf(m, L[j]);
        m = fmaxf(m, __shfl_xor(m, 1));
        float sum = 0.0f;
#pragma unroll
        for (int j = 0; j < 8; j++) if (j < nreal) sum += expf(L[j] - m);
        sum += __shfl_xor(sum, 1);
        float lse = m + logf(sum);
        float* op = out + (size_t)s.n * 10 + c * 8;
#pragma unroll
        for (int j = 0; j < 8; j++) if (j < nreal) op[j] = L[j] - lse;
    }
}

__global__ __launch_bounds__(CHAIN_THREADS, 4)
void chain_kernel(const float* __restrict__ x,
                  const int* __restrict__ rowbeg, const int* __restrict__ rowend,
                  const int* __restrict__ psrc, const float* __restrict__ dis,
                  const float* __restrict__ d2, const float* __restrict__ inv,
                  const float* __restrict__ W1, const float* __restrict__ b1,
                  const float* __restrict__ W2, const float* __restrict__ b2,
                  uint4* __restrict__ z0t, uint4* __restrict__ uz1t,
                  uint4* __restrict__ uz2t, uint4* __restrict__ uz3t,
                  uint4* __restrict__ z2rt, uint4* __restrict__ ub2t,
                  uint4* __restrict__ ub1t, uint4* __restrict__ w0t,
                  uint4* __restrict__ uw1t, uint4* __restrict__ uw2t,
                  uint4* __restrict__ uw3t, uint4* __restrict__ w2rt,
                  uint4* __restrict__ uv2t, uint4* __restrict__ uv1t,
                  float* __restrict__ out, int* __restrict__ gbar, int N) {
    __shared__ float sW1[2048];
    __shared__ float sW2[1024];   // W2 padded to 16 cols (zeros beyond col 9)
    __shared__ float sb1[16];
    __shared__ float sb2[16];
    for (int i = threadIdx.x; i < 2048; i += CHAIN_THREADS) sW1[i] = W1[i];
    for (int i = threadIdx.x; i < 1024; i += CHAIN_THREADS) {
        int k = i >> 8, rem = i & 255, j = rem >> 4, o = rem & 15;
        sW2[i] = (o < 10) ? W2[k * 160 + j * 10 + o] : 0.0f;
    }
    if (threadIdx.x < 16) {
        sb1[threadIdx.x] = b1[threadIdx.x];
        sb2[threadIdx.x] = (threadIdx.x < 10) ? b2[threadIdx.x] : 0.0f;
    }
    __syncthreads();

    int gtid = blockIdx.x * CHAIN_THREADS + threadIdx.x;
    int slot = gtid >> 2;
    int l = gtid & 3;
    int c = l & 1;
    int hf = l >> 1;

    // balanced node partition: each slot owns 1 or 2 nodes, evenly interleaved
    int nA = (int)(((long long)slot * N) >> 16);
    int nB = (int)(((long long)(slot + 1) * N) >> 16);
    int ncnt = nB - nA;   // always >= 1 for N=100000

    NodeSt ns[2];
    // safe defaults for ns[1] (guards keep it unused when ncnt==1, but avoid
    // speculative garbage addresses)
    ns[1].n = nA; ns[1].gb = 0; ns[1].ge = 0; ns[1].dz = 1;
    ns[1].f = 0.f; ns[1].dn = 0.f; ns[1].iv = 0.f;
#pragma unroll
    for (int j = 0; j < 8; j++) ns[1].pc[j] = 0;
#pragma unroll
    for (int i = 0; i < 2; i++)
        if (i < ncnt) node_init(ns[i], nA + i, hf, rowbeg, rowend, dis, d2, inv, psrc);

#pragma unroll
    for (int i = 0; i < 2; i++)
        if (i < ncnt) phaseZ(ns[i], x, sW1, c, hf, z0t, uz1t, uz2t, uz3t, z2rt);
    grid_barrier(gbar, CHAIN_BLOCKS * 1);
#pragma unroll
    for (int i = 0; i < 2; i++)
        if (i < ncnt) phaseP<false>(ns[i], psrc, uz3t, uz2t, nullptr, ub2t, c, hf);
    grid_barrier(gbar, CHAIN_BLOCKS * 2);
#pragma unroll
    for (int i = 0; i < 2; i++)
        if (i < ncnt) phaseP<true>(ns[i], psrc, ub2t, uz1t, uz3t, ub1t, c, hf);
    grid_barrier(gbar, CHAIN_BLOCKS * 3);
#pragma unroll
    for (int i = 0; i < 2; i++)
        if (i < ncnt) phaseF1(ns[i], psrc, ub1t, ub2t, z0t, z2rt, sW2, sb1,
                              w0t, uw1t, uw2t, uw3t, w2rt, c, hf);
    grid_barrier(gbar, CHAIN_BLOCKS * 4);
#pragma unroll
    for (int i = 0; i < 2; i++)
        if (i < ncnt) phaseP<false>(ns[i], psrc, uw3t, uw2t, nullptr, uv2t, c, hf);
    grid_barrier(gbar, CHAIN_BLOCKS * 5);
#pragma unroll
    for (int i = 0; i < 2; i++)
        if (i < ncnt) phaseP<true>(ns[i], psrc, uv2t, uw1t, uw3t, uv1t, c, hf);
    grid_barrier(gbar, CHAIN_BLOCKS * 6);
#pragma unroll
    for (int i = 0; i < 2; i++)
        if (i < ncnt) phaseF2(ns[i], psrc, uv1t, uv2t, w0t, w2rt, sb2, out, c, hf);
}

extern "C" void kernel_launch(void* const* d_in, const int* in_sizes, int n_in,
                              void* d_out, int out_size, void* d_ws, size_t ws_size,
                              hipStream_t stream) {
    const float* x  = (const float*)d_in[0];
    const int*   ei = (const int*)d_in[1];
    const float* W1 = (const float*)d_in[2];
    const float* b1 = (const float*)d_in[3];
    const float* W2 = (const float*)d_in[4];
    const float* b2 = (const float*)d_in[5];
    float* out = (float*)d_out;

    const int N = in_sizes[0] / 32;   // 100000
    const int E = in_sizes[1] / 2;    // 1600000
    const int* src = ei;
    const int* dst = ei + E;

    const int nbuck = (N + 511) / 512;        // 196

    // workspace layout (16B-aligned); all feature tables are N x 32B (2 uint4)
    char* w = (char*)d_ws;
    int*   bfill  = (int*)w;              w += NBUCK_MAX * 4;
    int*   gbar   = (int*)w;              w += 16 * 4;
    int*   rowbeg = (int*)w;              w += (size_t)(N + 4) * 4;
    int*   rowend = (int*)w;              w += (size_t)(N + 4) * 4;
    float* dis    = (float*)w;            w += (size_t)N * 4;
    float* d2     = (float*)w;            w += (size_t)N * 4;
    float* inv    = (float*)w;            w += (size_t)N * 4;
    int*   tmp    = (int*)w;              w += (size_t)NBUCK_MAX * CAPB * 4;
    int*   psrc   = (int*)w;              w += (size_t)NBUCK_MAX * CAPB * 4;
    uint4* z0t    = (uint4*)w;            w += (size_t)32 * N;
    uint4* uz1t   = (uint4*)w;            w += (size_t)32 * N;
    uint4* uz2t   = (uint4*)w;            w += (size_t)32 * N;
    uint4* uz3t   = (uint4*)w;            w += (size_t)32 * N;
    uint4* z2rt   = (uint4*)w;            w += (size_t)32 * N;
    uint4* ub2t   = (uint4*)w;            w += (size_t)32 * N;
    uint4* ub1t   = (uint4*)w;            w += (size_t)32 * N;
    uint4* w0t    = (uint4*)w;            w += (size_t)32 * N;
    uint4* uw1t   = (uint4*)w;            w += (size_t)32 * N;
    uint4* uw2t   = (uint4*)w;            w += (size_t)32 * N;
    uint4* uw3t   = (uint4*)w;            w += (size_t)32 * N;
    uint4* w2rt   = (uint4*)w;            w += (size_t)32 * N;
    uint4* uv2t   = (uint4*)w;            w += (size_t)32 * N;
    uint4* uv1t   = (uint4*)w;            w += (size_t)32 * N;

    int gCH = (E + CHUNK - 1) / CHUNK;

    // ---- CSR build ----
    hipMemsetAsync(bfill, 0, (NBUCK_MAX + 16) * sizeof(int), stream);
    binned_scatter_kernel<<<gCH, BLK, 0, stream>>>(src, dst, bfill, tmp, E, nbuck);
    bucket_place_kernel<<<nbuck, BLKP, 0, stream>>>(bfill, tmp, psrc, rowbeg, rowend,
                                                    dis, d2, inv, N);

    // ---- fused chain: zgen + 4x prop + final1 + final2 ----
    chain_kernel<<<CHAIN_BLOCKS, CHAIN_THREADS, 0, stream>>>(
        x, rowbeg, rowend, psrc, dis, d2, inv, W1, b1, W2, b2,
        z0t, uz1t, uz2t, uz3t, z2rt, ub2t, ub1t,
        w0t, uw1t, uw2t, uw3t, w2rt, uv2t, uv1t, out, gbar, N);
}

// Round 2
// 254.905 us; speedup vs baseline: 11.2942x; 11.2942x over previous
//
#include <hip/hip_runtime.h>
#include <hip/hip_bf16.h>
#include <math.h>

// ChebyNet: 2-layer ChebConv (K=4), N=100000, E=1600000, F 32->16->10, log_softmax.
//
// R23: revert R22's persistent-kernel fusion (software grid barriers with
// device-scope fences caused an L2 invalidation storm across the 8
// non-coherent XCD L2s -> every gather missed to HBM; 2879us vs 246us).
// Back to the split-kernel R21 structure, with one change: zgen no longer
// needs dis[n] (U-space scaling moved into prop1: gather applies dis[src]
// per edge, epilogue applies dis[n] to the add/sub terms -> algebraically
// identical), so zgen is merged into the binned_scatter dispatch as a
// block-role split. Scatter blocks are LDS-atomic/memory-bound, zgen blocks
// are VALU-bound -> they co-schedule; one fewer launch; one fewer table
// write (zgen now writes 4 plain tables instead of 5 scaled ones).
// R18-R21 recap: Clenshaw in 16-feature bf16 U-space, bucket CSR build,
// src-quartile edge ordering, deg-0 exact fallback, 4-lane prop split.

#define BLK 256
#define BLKP 512
#define NBUCK_MAX 256   // buckets = ceil(N/512); requires N <= 131072
#define CHUNK 4096      // edges per binned_scatter block
#define CAPB 16384      // fixed capacity per bucket region in tmp/psrc
#define PLACE_CAP 10240 // LDS staging capacity in bucket_place (avg bucket 8192)

// ---------- bf16 helpers (storage-only quantization) ----------
__device__ inline unsigned short f32_to_bf16_rne(float f) {
    unsigned int u = __float_as_uint(f);
    unsigned int rounding = 0x7FFFu + ((u >> 16) & 1u);
    return (unsigned short)((u + rounding) >> 16);
}
__device__ inline unsigned int pack_bf16x2(float a, float b) {
    return (unsigned int)f32_to_bf16_rne(a) | ((unsigned int)f32_to_bf16_rne(b) << 16);
}
__device__ inline void unpack8(const uint4 u, float* f) {
    const unsigned int* p = &u.x;
#pragma unroll
    for (int j = 0; j < 4; j++) {
        unsigned int w = p[j];
        f[2 * j]     = __uint_as_float(w << 16);
        f[2 * j + 1] = __uint_as_float(w & 0xFFFF0000u);
    }
}
__device__ inline void add8(const uint4 u, float* acc) {
    const unsigned int* p = &u.x;
#pragma unroll
    for (int j = 0; j < 4; j++) {
        unsigned int w = p[j];
        acc[2 * j]     += __uint_as_float(w << 16);
        acc[2 * j + 1] += __uint_as_float(w & 0xFFFF0000u);
    }
}
__device__ inline void fma8(const uint4 u, float wgt, float* acc) {
    const unsigned int* p = &u.x;
#pragma unroll
    for (int j = 0; j < 4; j++) {
        unsigned int w = p[j];
        acc[2 * j]     += wgt * __uint_as_float(w << 16);
        acc[2 * j + 1] += wgt * __uint_as_float(w & 0xFFFF0000u);
    }
}
__device__ inline uint4 pack8(const float* r) {
    uint4 o;
    o.x = pack_bf16x2(r[0], r[1]);
    o.y = pack_bf16x2(r[2], r[3]);
    o.z = pack_bf16x2(r[4], r[5]);
    o.w = pack_bf16x2(r[6], r[7]);
    return o;
}

// gather-sum over psrc[b,e) of vb chunk c
__device__ inline void gather_sum(const int* __restrict__ psrc, int b, int e,
                                  const uint4* __restrict__ vb, int c, float* acc) {
    int i = b;
    for (; i + 7 < e; i += 8) {
        int s0 = psrc[i],     s1 = psrc[i + 1], s2 = psrc[i + 2], s3 = psrc[i + 3];
        int s4 = psrc[i + 4], s5 = psrc[i + 5], s6 = psrc[i + 6], s7 = psrc[i + 7];
        uint4 a0 = vb[(size_t)s0 * 2 + c];
        uint4 a1 = vb[(size_t)s1 * 2 + c];
        uint4 a2 = vb[(size_t)s2 * 2 + c];
        uint4 a3 = vb[(size_t)s3 * 2 + c];
        uint4 a4 = vb[(size_t)s4 * 2 + c];
        uint4 a5 = vb[(size_t)s5 * 2 + c];
        uint4 a6 = vb[(size_t)s6 * 2 + c];
        uint4 a7 = vb[(size_t)s7 * 2 + c];
        add8(a0, acc); add8(a1, acc); add8(a2, acc); add8(a3, acc);
        add8(a4, acc); add8(a5, acc); add8(a6, acc); add8(a7, acc);
    }
    for (; i + 3 < e; i += 4) {
        int s0 = psrc[i], s1 = psrc[i + 1], s2 = psrc[i + 2], s3 = psrc[i + 3];
        uint4 a0 = vb[(size_t)s0 * 2 + c];
        uint4 a1 = vb[(size_t)s1 * 2 + c];
        uint4 a2 = vb[(size_t)s2 * 2 + c];
        uint4 a3 = vb[(size_t)s3 * 2 + c];
        add8(a0, acc); add8(a1, acc); add8(a2, acc); add8(a3, acc);
    }
    for (; i < e; i++) add8(vb[(size_t)psrc[i] * 2 + c], acc);
}

// gather-sum with per-edge dis[src] weight (prop1 only: U-space established here)
__device__ inline void gather_sum_dis(const int* __restrict__ psrc, int b, int e,
                                      const uint4* __restrict__ vb, int c,
                                      const float* __restrict__ dis, float* acc) {
    int i = b;
    for (; i + 7 < e; i += 8) {
        int s0 = psrc[i],     s1 = psrc[i + 1], s2 = psrc[i + 2], s3 = psrc[i + 3];
        int s4 = psrc[i + 4], s5 = psrc[i + 5], s6 = psrc[i + 6], s7 = psrc[i + 7];
        float d0 = dis[s0], d1 = dis[s1], d2v = dis[s2], d3 = dis[s3];
        float d4 = dis[s4], d5 = dis[s5], d6v = dis[s6], d7 = dis[s7];
        uint4 a0 = vb[(size_t)s0 * 2 + c];
        uint4 a1 = vb[(size_t)s1 * 2 + c];
        uint4 a2 = vb[(size_t)s2 * 2 + c];
        uint4 a3 = vb[(size_t)s3 * 2 + c];
        uint4 a4 = vb[(size_t)s4 * 2 + c];
        uint4 a5 = vb[(size_t)s5 * 2 + c];
        uint4 a6 = vb[(size_t)s6 * 2 + c];
        uint4 a7 = vb[(size_t)s7 * 2 + c];
        fma8(a0, d0, acc); fma8(a1, d1, acc); fma8(a2, d2v, acc); fma8(a3, d3, acc);
        fma8(a4, d4, acc); fma8(a5, d5, acc); fma8(a6, d6v, acc); fma8(a7, d7, acc);
    }
    for (; i + 3 < e; i += 4) {
        int s0 = psrc[i], s1 = psrc[i + 1], s2 = psrc[i + 2], s3 = psrc[i + 3];
        float d0 = dis[s0], d1 = dis[s1], d2v = dis[s2], d3 = dis[s3];
        uint4 a0 = vb[(size_t)s0 * 2 + c];
        uint4 a1 = vb[(size_t)s1 * 2 + c];
        uint4 a2 = vb[(size_t)s2 * 2 + c];
        uint4 a3 = vb[(size_t)s3 * 2 + c];
        fma8(a0, d0, acc); fma8(a1, d1, acc); fma8(a2, d2v, acc); fma8(a3, d3, acc);
    }
    for (; i < e; i++) {
        int s = psrc[i];
        fma8(vb[(size_t)s * 2 + c], dis[s], acc);
    }
}

// ---------- fused: CSR binned scatter (blocks < gCH) + zgen (blocks >= gCH) ----------
// zgen no longer depends on the CSR build (no dis scaling), so its blocks run
// concurrently with the scatter blocks in the same dispatch.
__global__ __launch_bounds__(BLK)
void scatter_zgen_kernel(const int* __restrict__ src, const int* __restrict__ dst,
                         int* __restrict__ bfill, int* __restrict__ tmp,
                         int E, int nbuck,
                         const float* __restrict__ x, const float* __restrict__ W1,
                         uint4* __restrict__ z0t, uint4* __restrict__ z1t,
                         uint4* __restrict__ z2t, uint4* __restrict__ z3t,
                         int N, int gCH) {
    int tid = threadIdx.x;
    if ((int)blockIdx.x < gCH) {
        // ---- binned scatter (identical to R21) ----
        __shared__ int cnt[NBUCK_MAX];
        __shared__ int lofs[NBUCK_MAX + 1];
        __shared__ int pos[NBUCK_MAX];
        __shared__ int gbase[NBUCK_MAX];
        __shared__ int stage[CHUNK];
        __shared__ unsigned char bkt[CHUNK];

        int e0 = blockIdx.x * CHUNK;
        int nE = min(CHUNK, E - e0);

        for (int b = tid; b < nbuck; b += BLK) { cnt[b] = 0; pos[b] = 0; }
        __syncthreads();

        for (int i = tid; i < nE; i += BLK) {
            int d = dst[e0 + i];
            atomicAdd(&cnt[d >> 9], 1);
        }
        __syncthreads();

        {
            int v = (tid < nbuck) ? cnt[tid] : 0;
            lofs[tid] = v;
            __syncthreads();
            for (int off = 1; off < BLK; off <<= 1) {
                int t = (tid >= off) ? lofs[tid - off] : 0;
                __syncthreads();
                lofs[tid] += t;
                __syncthreads();
            }
            int incl = lofs[tid];
            __syncthreads();
            lofs[tid] = incl - v;
            if (tid == 0) lofs[nbuck] = nE;
            if (tid < nbuck && v > 0)
                gbase[tid] = tid * CAPB + atomicAdd(&bfill[tid], v);
        }
        __syncthreads();

        for (int i = tid; i < nE; i += BLK) {
            int s = src[e0 + i];
            int d = dst[e0 + i];
            int b = d >> 9;
            int slot = lofs[b] + atomicAdd(&pos[b], 1);
            stage[slot] = (s << 9) | (d & 511);
            bkt[slot] = (unsigned char)b;
        }
        __syncthreads();

        for (int i = tid; i < nE; i += BLK) {
            int b = bkt[i];
            tmp[gbase[b] + (i - lofs[b])] = stage[i];
        }
    } else {
        // ---- zgen: z_k = x @ W1[k], PLAIN (no dis scaling); 2 lanes/node ----
        __shared__ float sW[4 * 32 * 16];
        for (int i = tid; i < 4 * 32 * 16; i += BLK) sW[i] = W1[i];
        __syncthreads();
        int t = ((int)blockIdx.x - gCH) * BLK + tid;
        int n = t >> 1;
        int h = t & 1;
        if (n >= N) return;
        float acc0[8], acc1[8], acc2[8], acc3[8];
#pragma unroll
        for (int j = 0; j < 8; j++) { acc0[j] = 0.f; acc1[j] = 0.f; acc2[j] = 0.f; acc3[j] = 0.f; }
        const float4* x4 = reinterpret_cast<const float4*>(x + (size_t)n * 32);
#pragma unroll
        for (int q = 0; q < 8; q++) {
            float4 a = x4[q];
            float xi[4] = {a.x, a.y, a.z, a.w};
#pragma unroll
            for (int u = 0; u < 4; u++) {
                const float* Wb = sW + (q * 4 + u) * 16 + h * 8;
                float xv = xi[u];
#pragma unroll
                for (int j = 0; j < 8; j++) {
                    acc0[j] += xv * Wb[j];
                    acc1[j] += xv * Wb[512 + j];
                    acc2[j] += xv * Wb[1024 + j];
                    acc3[j] += xv * Wb[1536 + j];
                }
            }
        }
        size_t o = (size_t)n * 2 + h;
        z0t[o] = pack8(acc0);
        z1t[o] = pack8(acc1);
        z2t[o] = pack8(acc2);
        z3t[o] = pack8(acc3);
    }
}

// Phase 2: per-bucket degree count/scan -> rowbeg/rowend/dis/d2/inv;
// rank+stage+flush psrc with each node's edges ordered by src quartile.
__global__ __launch_bounds__(BLKP)
void bucket_place_kernel(const int* __restrict__ bfill, const int* __restrict__ tmp,
                         int* __restrict__ psrc, int* __restrict__ rowbeg,
                         int* __restrict__ rowend, float* __restrict__ dis,
                         float* __restrict__ d2, float* __restrict__ inv, int N) {
    __shared__ int cnt4[512 * 4];
    __shared__ int ofs[512];
    __shared__ int fill4[512 * 4];
    __shared__ int stage[PLACE_CAP];

    int b = blockIdx.x;
    int tid = threadIdx.x;
    int n0 = b << 9;
    int nn = min(512, N - n0);
    int S = b * CAPB;
    int tot = bfill[b];

    int t1 = N >> 2, t2 = N >> 1, t3 = t2 + t1;

    for (int i = tid; i < 512 * 4; i += BLKP) { cnt4[i] = 0; fill4[i] = 0; }
    __syncthreads();

    for (int i = tid; i < tot; i += BLKP) {
        int rec = tmp[S + i];
        int nl = rec & 511;
        int s = rec >> 9;
        int q = (s >= t2) ? ((s >= t3) ? 3 : 2) : ((s >= t1) ? 1 : 0);
        atomicAdd(&cnt4[nl * 4 + q], 1);
    }
    __syncthreads();

    int c0 = cnt4[tid * 4 + 0], c1 = cnt4[tid * 4 + 1];
    int c2 = cnt4[tid * 4 + 2], c3 = cnt4[tid * 4 + 3];
    int v = c0 + c1 + c2 + c3;
    cnt4[tid * 4 + 0] = 0;
    cnt4[tid * 4 + 1] = c0;
    cnt4[tid * 4 + 2] = c0 + c1;
    cnt4[tid * 4 + 3] = c0 + c1 + c2;
    ofs[tid] = v;
    __syncthreads();
    for (int off = 1; off < 512; off <<= 1) {
        int t = (tid >= off) ? ofs[tid - off] : 0;
        __syncthreads();
        ofs[tid] += t;
        __syncthreads();
    }
    int excl = ofs[tid] - v;
    __syncthreads();
    ofs[tid] = excl;
    if (tid < nn) {
        int n = n0 + tid;
        rowbeg[n] = S + excl;
        rowend[n] = S + excl + v;
        float fv = (float)v;
        dis[n] = (v > 0) ? rsqrtf(fv) : 0.0f;
        d2[n]  = (v > 0) ? 1.0f / fv : 0.0f;
        inv[n] = (v > 0) ? sqrtf(fv) : 0.0f;
    }
    __syncthreads();

    if (tot <= PLACE_CAP) {
        for (int i = tid; i < tot; i += BLKP) {
            int rec = tmp[S + i];
            int nl = rec & 511;
            int s = rec >> 9;
            int q = (s >= t2) ? ((s >= t3) ? 3 : 2) : ((s >= t1) ? 1 : 0);
            int slot = ofs[nl] + cnt4[nl * 4 + q] + atomicAdd(&fill4[nl * 4 + q], 1);
            stage[slot] = s;
        }
        __syncthreads();
        for (int i = tid; i < tot; i += BLKP) psrc[S + i] = stage[i];
    } else {
        for (int i = tid; i < tot; i += BLKP) {
            int rec = tmp[S + i];
            int nl = rec & 511;
            int s = rec >> 9;
            int q = (s >= t2) ? ((s >= t3) ? 3 : 2) : ((s >= t1) ? 1 : 0);
            int slot = S + ofs[nl] + cnt4[nl * 4 + q] + atomicAdd(&fill4[nl * 4 + q], 1);
            psrc[slot] = s;
        }
    }
}

// prop1 (U-space establishment): ub2 = -2*d2[n]*Sum_s dis[s]*z3[s] + dis[n]*z2[n]
// 4 lanes/node: lane l -> chunk c=l&1, edge-half hf=l>>1.
__global__ __launch_bounds__(BLK)
void prop1_kernel(const int* __restrict__ rowbeg, const int* __restrict__ rowend,
                  const int* __restrict__ psrc, const float* __restrict__ d2,
                  const float* __restrict__ dis,
                  const uint4* __restrict__ z3t, const uint4* __restrict__ z2t,
                  uint4* __restrict__ ub2t, int N) {
    int t = blockIdx.x * blockDim.x + threadIdx.x;
    int n = t >> 2;
    int l = t & 3;
    int c = l & 1;
    int hf = l >> 1;
    if (n >= N) return;
    int beg = rowbeg[n];
    int end = rowend[n];
    int mid = beg + ((end - beg) >> 1);
    int b = hf ? mid : beg;
    int e = hf ? end : mid;
    float acc[8];
#pragma unroll
    for (int j = 0; j < 8; j++) acc[j] = 0.f;
    gather_sum_dis(psrc, b, e, z3t, c, dis, acc);
#pragma unroll
    for (int j = 0; j < 8; j++) acc[j] += __shfl_xor(acc[j], 2);
    if (hf) return;
    float f = -2.0f * d2[n];
    float dn = dis[n];
    float ad[8], r[8];
    unpack8(z2t[(size_t)n * 2 + c], ad);
#pragma unroll
    for (int j = 0; j < 8; j++) r[j] = f * acc[j] + dn * ad[j];
    ub2t[(size_t)n * 2 + c] = pack8(r);
}

// prop2: ub1 = -2*d2[n]*Sum_s ub2[s] + dis[n]*(z1[n] - z3[n])
__global__ __launch_bounds__(BLK)
void prop2_kernel(const int* __restrict__ rowbeg, const int* __restrict__ rowend,
                  const int* __restrict__ psrc, const float* __restrict__ d2,
                  const float* __restrict__ dis,
                  const uint4* __restrict__ ub2t, const uint4* __restrict__ z1t,
                  const uint4* __restrict__ z3t, uint4* __restrict__ ub1t, int N) {
    int t = blockIdx.x * blockDim.x + threadIdx.x;
    int n = t >> 2;
    int l = t & 3;
    int c = l & 1;
    int hf = l >> 1;
    if (n >= N) return;
    int beg = rowbeg[n];
    int end = rowend[n];
    int mid = beg + ((end - beg) >> 1);
    int b = hf ? mid : beg;
    int e = hf ? end : mid;
    float acc[8];
#pragma unroll
    for (int j = 0; j < 8; j++) acc[j] = 0.f;
    gather_sum(psrc, b, e, ub2t, c, acc);
#pragma unroll
    for (int j = 0; j < 8; j++) acc[j] += __shfl_xor(acc[j], 2);
    if (hf) return;
    float f = -2.0f * d2[n];
    float dn = dis[n];
    float ad[8], sb[8], r[8];
    unpack8(z1t[(size_t)n * 2 + c], ad);
    unpack8(z3t[(size_t)n * 2 + c], sb);
#pragma unroll
    for (int j = 0; j < 8; j++) r[j] = f * acc[j] + dn * (ad[j] - sb[j]);
    ub1t[(size_t)n * 2 + c] = pack8(r);
}

// Clenshaw prop (layer 2, U-space add/sub tables), 4 lanes/node.
template <bool HAVE_SUB>
__global__ __launch_bounds__(BLK)
void prop_cl_kernel(const int* __restrict__ rowbeg, const int* __restrict__ rowend,
                    const int* __restrict__ psrc, const float* __restrict__ d2,
                    const uint4* __restrict__ vb, const uint4* __restrict__ addt,
                    const uint4* __restrict__ subt, uint4* __restrict__ outb, int N) {
    int t = blockIdx.x * blockDim.x + threadIdx.x;
    int n = t >> 2;
    int l = t & 3;
    int c = l & 1;
    int hf = l >> 1;
    if (n >= N) return;
    int beg = rowbeg[n];
    int end = rowend[n];
    int mid = beg + ((end - beg) >> 1);
    int b = hf ? mid : beg;
    int e = hf ? end : mid;
    float acc[8];
#pragma unroll
    for (int j = 0; j < 8; j++) acc[j] = 0.f;
    gather_sum(psrc, b, e, vb, c, acc);
#pragma unroll
    for (int j = 0; j < 8; j++) acc[j] += __shfl_xor(acc[j], 2);
    if (hf) return;
    float f = -2.0f * d2[n];
    float ad[8], r[8];
    unpack8(addt[(size_t)n * 2 + c], ad);
    if (HAVE_SUB) {
        float sb[8];
        unpack8(subt[(size_t)n * 2 + c], sb);
#pragma unroll
        for (int j = 0; j < 8; j++) r[j] = f * acc[j] + ad[j] - sb[j];
    } else {
#pragma unroll
        for (int j = 0; j < 8; j++) r[j] = f * acc[j] + ad[j];
    }
    outb[(size_t)n * 2 + c] = pack8(r);
}

// final1 (2-lane form): S = z0 - dis*Sum Ub1[src] - inv*Ub2 (deg-0: z0 - z2);
// h = relu(b1+S); w_k = h @ W2[k] (16-padded cols).
__global__ __launch_bounds__(BLK)
void final1_kernel(const int* __restrict__ rowbeg, const int* __restrict__ rowend,
                   const int* __restrict__ psrc, const float* __restrict__ dis,
                   const float* __restrict__ d2, const float* __restrict__ inv,
                   const uint4* __restrict__ ub1t, const uint4* __restrict__ ub2t,
                   const uint4* __restrict__ z0t, const uint4* __restrict__ z2t,
                   const float* __restrict__ W2, const float* __restrict__ b1,
                   uint4* __restrict__ w0t, uint4* __restrict__ uw1t,
                   uint4* __restrict__ uw2t, uint4* __restrict__ uw3t,
                   uint4* __restrict__ w2rt, int N) {
    __shared__ float sW[4 * 16 * 16];   // W2 padded to 16 cols (zeros beyond col 9)
    __shared__ float sb1[16];
    for (int i = threadIdx.x; i < 4 * 16 * 16; i += blockDim.x) {
        int k = i >> 8, rem = i & 255, j = rem >> 4, o = rem & 15;
        sW[i] = (o < 10) ? W2[k * 160 + j * 10 + o] : 0.0f;
    }
    if (threadIdx.x < 16) sb1[threadIdx.x] = b1[threadIdx.x];
    __syncthreads();
    int t = blockIdx.x * blockDim.x + threadIdx.x;
    int n = t >> 1;
    int h = t & 1;
    if (n >= N) return;
    int beg = rowbeg[n];
    int end = rowend[n];
    float acc[8];
#pragma unroll
    for (int j = 0; j < 8; j++) acc[j] = 0.f;
    gather_sum(psrc, beg, end, ub1t, h, acc);
    size_t o2 = (size_t)n * 2 + h;
    float z0[8], hrow[8];
    unpack8(z0t[o2], z0);
    if (d2[n] == 0.0f) {   // deg-0: S = z0 - z2
        float z2[8];
        unpack8(z2t[o2], z2);
#pragma unroll
        for (int j = 0; j < 8; j++) hrow[j] = fmaxf(sb1[h * 8 + j] + z0[j] - z2[j], 0.0f);
    } else {
        float b2v[8];
        unpack8(ub2t[o2], b2v);
        float dn = dis[n], iv = inv[n];
#pragma unroll
        for (int j = 0; j < 8; j++)
            hrow[j] = fmaxf(sb1[h * 8 + j] + z0[j] - dn * acc[j] - iv * b2v[j], 0.0f);
    }
    // exchange halves -> full h16
    float h16[16];
#pragma unroll
    for (int j = 0; j < 8; j++) {
        float other = __shfl_xor(hrow[j], 1);
        h16[h * 8 + j] = hrow[j];
        h16[(1 - h) * 8 + j] = other;
    }
    // w_k = h @ W2[k], this lane's 8 output cols (h*8 .. h*8+7)
    float w0[8], w1[8], w2[8], w3[8];
#pragma unroll
    for (int o = 0; o < 8; o++) { w0[o] = 0.f; w1[o] = 0.f; w2[o] = 0.f; w3[o] = 0.f; }
#pragma unroll
    for (int j = 0; j < 16; j++) {
        float hv = h16[j];
        const float* Wb = sW + j * 16 + h * 8;
#pragma unroll
        for (int o = 0; o < 8; o++) {
            w0[o] += hv * Wb[o];
            w1[o] += hv * Wb[256 + o];
            w2[o] += hv * Wb[512 + o];
            w3[o] += hv * Wb[768 + o];
        }
    }
    float dn = dis[n];
    float s1[8], s2[8], s3[8];
#pragma unroll
    for (int o = 0; o < 8; o++) { s1[o] = dn * w1[o]; s2[o] = dn * w2[o]; s3[o] = dn * w3[o]; }
    w0t[o2]  = pack8(w0);
    uw1t[o2] = pack8(s1);
    uw2t[o2] = pack8(s2);
    w2rt[o2] = pack8(w2);
    uw3t[o2] = pack8(s3);
}

// final2, 4 lanes/node: L = w0 - dis*Sum Uv1[src] - inv*Uv2 (deg-0: w0 - w2r);
// logits = b2 + L; log_softmax on half-0 lanes; lane0 writes 8, lane1 writes 2.
__global__ __launch_bounds__(BLK)
void final2_kernel(const int* __restrict__ rowbeg, const int* __restrict__ rowend,
                   const int* __restrict__ psrc, const float* __restrict__ dis,
                   const float* __restrict__ d2, const float* __restrict__ inv,
                   const uint4* __restrict__ uv1t, const uint4* __restrict__ uv2t,
                   const uint4* __restrict__ w0t, const uint4* __restrict__ w2rt,
                   const float* __restrict__ b2, float* __restrict__ out, int N) {
    __shared__ float sb2[16];
    if (threadIdx.x < 16) sb2[threadIdx.x] = (threadIdx.x < 10) ? b2[threadIdx.x] : 0.0f;
    __syncthreads();
    int t = blockIdx.x * blockDim.x + threadIdx.x;
    int n = t >> 2;
    int l = t & 3;
    int c = l & 1;
    int hf = l >> 1;
    if (n >= N) return;
    int beg = rowbeg[n];
    int end = rowend[n];
    int mid = beg + ((end - beg) >> 1);
    int gb = hf ? mid : beg;
    int ge = hf ? end : mid;
    float acc[8];
#pragma unroll
    for (int j = 0; j < 8; j++) acc[j] = 0.f;
    gather_sum(psrc, gb, ge, uv1t, c, acc);
#pragma unroll
    for (int j = 0; j < 8; j++) acc[j] += __shfl_xor(acc[j], 2);
    if (hf) return;
    size_t o2 = (size_t)n * 2 + c;
    float w0[8], L[8];
    unpack8(w0t[o2], w0);
    if (d2[n] == 0.0f) {
        float w2[8];
        unpack8(w2rt[o2], w2);
#pragma unroll
        for (int j = 0; j < 8; j++) L[j] = sb2[c * 8 + j] + w0[j] - w2[j];
    } else {
        float v2[8];
        unpack8(uv2t[o2], v2);
        float dn = dis[n], iv = inv[n];
#pragma unroll
        for (int j = 0; j < 8; j++)
            L[j] = sb2[c * 8 + j] + w0[j] - dn * acc[j] - iv * v2[j];
    }
    int nreal = (c == 0) ? 8 : 2;   // lane1 holds cols 8,9 (+6 pads)
    float m = -3.0e38f;
    for (int j = 0; j < nreal; j++) m = fmaxf(m, L[j]);
    m = fmaxf(m, __shfl_xor(m, 1));
    float s = 0.0f;
    for (int j = 0; j < nreal; j++) s += expf(L[j] - m);
    s += __shfl_xor(s, 1);
    float lse = m + logf(s);
    float* op = out + (size_t)n * 10 + c * 8;
    for (int j = 0; j < nreal; j++) op[j] = L[j] - lse;
}

extern "C" void kernel_launch(void* const* d_in, const int* in_sizes, int n_in,
                              void* d_out, int out_size, void* d_ws, size_t ws_size,
                              hipStream_t stream) {
    const float* x  = (const float*)d_in[0];
    const int*   ei = (const int*)d_in[1];
    const float* W1 = (const float*)d_in[2];
    const float* b1 = (const float*)d_in[3];
    const float* W2 = (const float*)d_in[4];
    const float* b2 = (const float*)d_in[5];
    float* out = (float*)d_out;

    const int N = in_sizes[0] / 32;   // 100000
    const int E = in_sizes[1] / 2;    // 1600000
    const int* src = ei;
    const int* dst = ei + E;

    const int nbuck = (N + 511) / 512;        // 196

    // workspace layout (16B-aligned); all feature tables are N x 32B (2 uint4)
    char* w = (char*)d_ws;
    int*   bfill  = (int*)w;              w += NBUCK_MAX * 4;
    int*   rowbeg = (int*)w;              w += (size_t)(N + 4) * 4;
    int*   rowend = (int*)w;              w += (size_t)(N + 4) * 4;
    float* dis    = (float*)w;            w += (size_t)N * 4;
    float* d2     = (float*)w;            w += (size_t)N * 4;
    float* inv    = (float*)w;            w += (size_t)N * 4;
    int*   tmp    = (int*)w;              w += (size_t)NBUCK_MAX * CAPB * 4;
    int*   psrc   = (int*)w;              w += (size_t)NBUCK_MAX * CAPB * 4;
    uint4* z0t    = (uint4*)w;            w += (size_t)32 * N;
    uint4* z1t    = (uint4*)w;            w += (size_t)32 * N;
    uint4* z2t    = (uint4*)w;            w += (size_t)32 * N;
    uint4* z3t    = (uint4*)w;            w += (size_t)32 * N;
    uint4* ub2t   = (uint4*)w;            w += (size_t)32 * N;
    uint4* ub1t   = (uint4*)w;            w += (size_t)32 * N;
    uint4* w0t    = (uint4*)w;            w += (size_t)32 * N;
    uint4* uw1t   = (uint4*)w;            w += (size_t)32 * N;
    uint4* uw2t   = (uint4*)w;            w += (size_t)32 * N;
    uint4* uw3t   = (uint4*)w;            w += (size_t)32 * N;
    uint4* w2rt   = (uint4*)w;            w += (size_t)32 * N;
    uint4* uv2t   = (uint4*)w;            w += (size_t)32 * N;
    uint4* uv1t   = (uint4*)w;            w += (size_t)32 * N;

    int gN2 = (N * 2 + BLK - 1) / BLK;    // 2 lanes/node (final1)
    int gN4 = (N * 4 + BLK - 1) / BLK;    // 4 lanes/node (props, final2)
    int gCH = (E + CHUNK - 1) / CHUNK;    // scatter blocks
    int gZ2 = gN2;                        // zgen blocks

    // ---- CSR build + zgen (independent -> fused dispatch, block-role split) ----
    hipMemsetAsync(bfill, 0, NBUCK_MAX * sizeof(int), stream);
    scatter_zgen_kernel<<<gCH + gZ2, BLK, 0, stream>>>(src, dst, bfill, tmp, E, nbuck,
                                                       x, W1, z0t, z1t, z2t, z3t, N, gCH);
    bucket_place_kernel<<<nbuck, BLKP, 0, stream>>>(bfill, tmp, psrc, rowbeg, rowend,
                                                    dis, d2, inv, N);

    // ---- layer 1 (Clenshaw in 16-feature domain; prop1 establishes U-space) ----
    prop1_kernel<<<gN4, BLK, 0, stream>>>(rowbeg, rowend, psrc, d2, dis,
                                          z3t, z2t, ub2t, N);
    prop2_kernel<<<gN4, BLK, 0, stream>>>(rowbeg, rowend, psrc, d2, dis,
                                          ub2t, z1t, z3t, ub1t, N);
    final1_kernel<<<gN2, BLK, 0, stream>>>(rowbeg, rowend, psrc, dis, d2, inv,
                                           ub1t, ub2t, z0t, z2t, W2, b1,
                                           w0t, uw1t, uw2t, uw3t, w2rt, N);

    // ---- layer 2 (Clenshaw in 10(->16)-feature domain) ----
    prop_cl_kernel<false><<<gN4, BLK, 0, stream>>>(rowbeg, rowend, psrc, d2,
                                                   uw3t, uw2t, nullptr, uv2t, N);
    prop_cl_kernel<true ><<<gN4, BLK, 0, stream>>>(rowbeg, rowend, psrc, d2,
                                                   uv2t, uw1t, uw3t, uv1t, N);
    final2_kernel<<<gN4, BLK, 0, stream>>>(rowbeg, rowend, psrc, dis, d2, inv,
                                           uv1t, uv2t, w0t, w2rt, b2, out, N);
}